// Round 4
// baseline (860.319 us; speedup 1.0000x reference)
//
#include <hip/hip_runtime.h>

#define NN 100000
#define NE 1600000
#define NT (2 * NN)        // combined nodes (sr | tg+NN)
#define ET (2 * NE)        // combined edges
#define DIM 128
#define NS 15000
#define SB2 ((NT + 255) / 256)  // 782 scan blocks
#define PAD 136                 // LDS row stride in bf16
#define NRANGE 8                // dst-range partition (1 range <-> 1 XCD)
#define RSZ (NT / NRANGE)       // 25000 nodes/range; LDS hist = 100 KB (<160 KB/CU)
#define CH 32                   // edge chunks
#define CI4 (ET / 4 / CH)       // 25000 i4-groups per chunk (exact)
#define NE4 (NE / 4)            // 400000

typedef __attribute__((ext_vector_type(8))) short frag_ab;  // 8 bf16
typedef __attribute__((ext_vector_type(4))) float frag_cd;  // 4 f32
typedef __attribute__((ext_vector_type(4))) int i4;

__device__ __forceinline__ unsigned short f2bf(float f) {  // RNE
    unsigned int u = __float_as_uint(f);
    u += 0x7fff + ((u >> 16) & 1);
    return (unsigned short)(u >> 16);
}
__device__ __forceinline__ float bflo(unsigned int u) { return __uint_as_float(u << 16); }
__device__ __forceinline__ float bfhi(unsigned int u) { return __uint_as_float(u & 0xffff0000u); }

// ---------------- pass 1: per-(range,chunk) LDS histogram -> P[c][node] ----------------
// Zero global atomics. Cacheable loads: the edge arrays are re-read x8 by design;
// let L2/L3 retain them for later range-blocks and for fillp_k.
__global__ __launch_bounds__(1024) void hist_k(const int* __restrict__ e_sr,
                                               const int* __restrict__ e_tg,
                                               int* __restrict__ P) {
    __shared__ int lc[RSZ];
    const int r = blockIdx.x & (NRANGE - 1);   // low bits -> XCD round-robin
    const int c = blockIdx.x >> 3;
    const int lo = r * RSZ;
    for (int i = threadIdx.x; i < RSZ; i += 1024) lc[i] = 0;
    __syncthreads();
    const int base = c * CI4;  // i4 units into the combined edge list
    for (int v = threadIdx.x; v < CI4; v += 1024) {
        i4 d4;
        if (c < 16) {
            d4 = *((const i4*)e_sr + NE4 + base + v);
        } else {
            d4 = *((const i4*)e_tg + base + v);
            d4 += NN;
        }
#pragma unroll
        for (int j = 0; j < 4; ++j) {
            const int t = d4[j] - lo;
            if ((unsigned)t < RSZ) atomicAdd(&lc[t], 1);
        }
    }
    __syncthreads();
    for (int i = threadIdx.x; i < RSZ; i += 1024) P[c * NT + lo + i] = lc[i];
}

// ---------------- cnt = sum_c P[c][n] ; fused dinv + scanA block sums ----------------
__global__ __launch_bounds__(256) void reduceA_k(const int* __restrict__ P,
                                                 int* __restrict__ cnt,
                                                 float* __restrict__ dinv,
                                                 int* __restrict__ bsum) {
    __shared__ int sh[256];
    const int t = threadIdx.x;
    const int i = blockIdx.x * 256 + t;
    int s = 0;
    if (i < NT) {
#pragma unroll
        for (int c = 0; c < CH; ++c) s += P[c * NT + i];
        cnt[i] = s;
        dinv[i] = rsqrtf((float)(s + 1));  // +1 self-loop
    }
    sh[t] = s;
    __syncthreads();
    for (int off = 128; off > 0; off >>= 1) {
        if (t < off) sh[t] += sh[t + off];
        __syncthreads();
    }
    if (t == 0) bsum[blockIdx.x] = sh[0];
}

__global__ __launch_bounds__(1024) void scanB_k(int* bsum, int* row_ptr) {
    __shared__ int s[1024];
    const int t = threadIdx.x;
    const int v = (t < SB2) ? bsum[t] : 0;
    s[t] = v;
    __syncthreads();
    for (int off = 1; off < 1024; off <<= 1) {
        int add = (t >= off) ? s[t - off] : 0;
        __syncthreads();
        s[t] += add;
        __syncthreads();
    }
    if (t < SB2) bsum[t] = s[t] - v;        // exclusive
    if (t == SB2 - 1) row_ptr[NT] = s[t];   // == ET
}

// ---------------- scanC + base fused: row_ptr + per-(chunk,node) slot bases ----------------
__global__ __launch_bounds__(256) void scanCbase_k(const int* __restrict__ cnt,
                                                   const int* __restrict__ bsum,
                                                   int* __restrict__ row_ptr,
                                                   int* __restrict__ P) {
    __shared__ int s[256];
    const int t = threadIdx.x;
    const int i = blockIdx.x * 256 + t;
    const int v = (i < NT) ? cnt[i] : 0;
    s[t] = v;
    __syncthreads();
    for (int off = 1; off < 256; off <<= 1) {
        int add = (t >= off) ? s[t - off] : 0;
        __syncthreads();
        s[t] += add;
        __syncthreads();
    }
    if (i < NT) {
        const int rp = bsum[blockIdx.x] + s[t] - v;
        row_ptr[i] = rp;
        int run = rp;
#pragma unroll
        for (int c = 0; c < CH; ++c) {
            const int pv = P[c * NT + i];
            P[c * NT + i] = run;
            run += pv;
        }
    }
}

// ---------------- pass 2: fill via LDS cursors, atomic-free globally ----------------
__global__ __launch_bounds__(1024) void fillp_k(const int* __restrict__ e_sr,
                                                const int* __restrict__ e_tg,
                                                const int* __restrict__ P,  // = base
                                                int* __restrict__ csr_src) {
    __shared__ int cur[RSZ];
    const int r = blockIdx.x & (NRANGE - 1);
    const int c = blockIdx.x >> 3;
    const int lo = r * RSZ;
    for (int i = threadIdx.x; i < RSZ; i += 1024) cur[i] = P[c * NT + lo + i];
    __syncthreads();
    const int base = c * CI4;
    for (int v = threadIdx.x; v < CI4; v += 1024) {
        i4 s4, d4;
        if (c < 16) {
            s4 = *((const i4*)e_sr + base + v);
            d4 = *((const i4*)e_sr + NE4 + base + v);
        } else {
            s4 = *((const i4*)e_tg + base + v - NE4);
            d4 = *((const i4*)e_tg + base + v);
            s4 += NN;
            d4 += NN;
        }
#pragma unroll
        for (int j = 0; j < 4; ++j) {
            const int t = d4[j] - lo;
            if ((unsigned)t < RSZ) {
                const int pos = atomicAdd(&cur[t], 1);
                csr_src[pos] = s4[j];  // plain store: wants L2 residency
            }
        }
    }
}

// ---------------- x~0 = bf16(dinv ⊙ emb), packed 2 ch / uint ----------------
__global__ __launch_bounds__(256) void convX2_k(const float* __restrict__ emb_sr,
                                                const float* __restrict__ emb_tg,
                                                const float* __restrict__ dinv,
                                                unsigned int* __restrict__ xq) {
    const int i = blockIdx.x * 256 + threadIdx.x;  // over NT*64 channel-pairs
    if (i >= NT * 64) return;
    const int node = i >> 6;  // wave-uniform (64 lanes = 1 node)
    const float d = dinv[node];
    float2 v = (node < NN) ? ((const float2*)emb_sr)[i]
                           : ((const float2*)emb_tg)[i - NN * 64];
    const unsigned int p = (unsigned int)f2bf(d * v.x) | ((unsigned int)f2bf(d * v.y) << 16);
    __builtin_nontemporal_store(p, &xq[i]);
}

// Wt[n][k] = bf16(W[k][n])
__global__ __launch_bounds__(256) void convW_k(const float* __restrict__ W,
                                               unsigned short* __restrict__ wt) {
    int i = blockIdx.x * 256 + threadIdx.x;
    if (i >= DIM * DIM) return;
    const int n = i & 127, k = i >> 7;
    wt[n * DIM + k] = f2bf(W[k * DIM + n]);
}

// ---------------- fused layer: aggregate x~ -> z (LDS) -> MFMA @ W -> relu ----------------
// out_t = relu(z_t @ W),  z_t = dinv_t * Σ_{s∈N(t)} x~_s + (dinv_t + 1/dinv_t) * x~_t
// (aggregation commutes with the linear W-transform; x~ = dinv ⊙ x).
// FINAL=false: write x~_next = bf16(dinv * out).  FINAL=true: write f32 out.
// Block: 256 thr = 4 waves; each wave gathers 16 node rows (2 ch/lane), z staged
// bf16 in LDS, then the proven 4-wave 64x128x128 MFMA tile with W read directly
// from global (32 KB, L1-resident — no W staging LDS).
template <bool FINAL>
__global__ __launch_bounds__(256, 4) void layer_k(const int* __restrict__ row_ptr,
                                                  const int* __restrict__ csr_src,
                                                  const float* __restrict__ dinv,
                                                  const unsigned int* __restrict__ X2,  // x~ packed
                                                  const unsigned short* __restrict__ Wt,
                                                  float* __restrict__ outf,
                                                  unsigned short* __restrict__ outq) {
    __shared__ unsigned short zs[64 * PAD];  // 17.4 KB
    const int tid = threadIdx.x;
    const int wave = tid >> 6;
    const int lane = tid & 63;
    const int node0 = blockIdx.x * 64;

    // ---- gather phase: wave pulls nodes [wave*16, wave*16+16) ----
    for (int r = wave * 16; r < wave * 16 + 16; ++r) {
        const int node = node0 + r;
        unsigned int zpack = 0;
        if (node < NT) {
            const int beg = row_ptr[node];
            const int end = row_ptr[node + 1];
            float sx = 0.f, sy = 0.f;
            for (int base = beg; base < end; base += 64) {
                int rem = end - base; if (rem > 64) rem = 64;
                const int sl = (lane < rem)
                    ? __builtin_nontemporal_load(&csr_src[base + lane]) : 0;
                int j = 0;
                for (; j + 8 <= rem; j += 8) {  // 8-deep for latency hiding
                    const int s0 = __shfl(sl, j + 0);
                    const int s1 = __shfl(sl, j + 1);
                    const int s2 = __shfl(sl, j + 2);
                    const int s3 = __shfl(sl, j + 3);
                    const int s4 = __shfl(sl, j + 4);
                    const int s5 = __shfl(sl, j + 5);
                    const int s6 = __shfl(sl, j + 6);
                    const int s7 = __shfl(sl, j + 7);
                    const unsigned int m0 = X2[s0 * 64 + lane];
                    const unsigned int m1 = X2[s1 * 64 + lane];
                    const unsigned int m2 = X2[s2 * 64 + lane];
                    const unsigned int m3 = X2[s3 * 64 + lane];
                    const unsigned int m4 = X2[s4 * 64 + lane];
                    const unsigned int m5 = X2[s5 * 64 + lane];
                    const unsigned int m6 = X2[s6 * 64 + lane];
                    const unsigned int m7 = X2[s7 * 64 + lane];
                    sx += bflo(m0) + bflo(m1) + bflo(m2) + bflo(m3)
                        + bflo(m4) + bflo(m5) + bflo(m6) + bflo(m7);
                    sy += bfhi(m0) + bfhi(m1) + bfhi(m2) + bfhi(m3)
                        + bfhi(m4) + bfhi(m5) + bfhi(m6) + bfhi(m7);
                }
                for (; j < rem; ++j) {
                    const int s = __shfl(sl, j);
                    const unsigned int mu = X2[s * 64 + lane];
                    sx += bflo(mu);
                    sy += bfhi(mu);
                }
            }
            const float d = dinv[node];
            const float cf = d + 1.0f / d;   // self: (dinv^2+1)*x = (d + 1/d)*x~
            const unsigned int xt = X2[node * 64 + lane];
            const float zx = d * sx + cf * bflo(xt);
            const float zy = d * sy + cf * bfhi(xt);
            zpack = (unsigned int)f2bf(zx) | ((unsigned int)f2bf(zy) << 16);
        }
        *(unsigned int*)&zs[r * PAD + lane * 2] = zpack;
    }
    __syncthreads();

    // ---- GEMM phase: z[64][128] @ W[128][128], proven tile/frag layout ----
    const int m = lane & 15;
    const int quad = lane >> 4;
    const int rbase = wave * 16;

    frag_cd acc[8];
#pragma unroll
    for (int ct = 0; ct < 8; ct++) acc[ct] = (frag_cd){0.f, 0.f, 0.f, 0.f};

#pragma unroll
    for (int ks = 0; ks < 4; ks++) {
        const frag_ab a = *(const frag_ab*)&zs[(rbase + m) * PAD + ks * 32 + quad * 8];
#pragma unroll
        for (int ct = 0; ct < 8; ct++) {
            const frag_ab b = *(const frag_ab*)&Wt[(ct * 16 + m) * DIM + ks * 32 + quad * 8];
            acc[ct] = __builtin_amdgcn_mfma_f32_16x16x32_bf16(a, b, acc[ct], 0, 0, 0);
        }
    }

    // C/D layout: col = lane&15, row = quad*4 + reg
#pragma unroll
    for (int r = 0; r < 4; r++) {
        const int grow = node0 + rbase + quad * 4 + r;
        if (grow < NT) {
            if (FINAL) {
#pragma unroll
                for (int ct = 0; ct < 8; ct++)
                    __builtin_nontemporal_store(fmaxf(acc[ct][r], 0.f),
                                                &outf[grow * DIM + ct * 16 + m]);
            } else {
                const float dv = dinv[grow];
#pragma unroll
                for (int ct = 0; ct < 8; ct++)
                    __builtin_nontemporal_store(f2bf(dv * fmaxf(acc[ct][r], 0.f)),
                                                &outq[grow * DIM + ct * 16 + m]);
            }
        }
    }
}

// ---------------- seed gather ----------------
__global__ __launch_bounds__(256) void gather_k(const int* __restrict__ seeds,
                                                const float* __restrict__ ent,
                                                float* __restrict__ out, int node_off) {
    const int gid = blockIdx.x * 256 + threadIdx.x;
    const int s = gid >> 5;
    if (s >= NS) return;
    const int q = gid & 31;
    ((float4*)out)[s * 32 + q] =
        ((const float4*)ent)[(seeds[s] + node_off) * 32 + q];
}

extern "C" void kernel_launch(void* const* d_in, const int* in_sizes, int n_in,
                              void* d_out, int out_size, void* d_ws, size_t ws_size,
                              hipStream_t stream) {
    const int* sr_seeds = (const int*)d_in[0];
    const int* tg_seeds = (const int*)d_in[1];
    const int* edges_sr = (const int*)d_in[2];
    const int* edges_tg = (const int*)d_in[3];
    const float* emb_sr = (const float*)d_in[4];
    const float* emb_tg = (const float*)d_in[5];
    const float* W0 = (const float*)d_in[6];
    const float* W1 = (const float*)d_in[7];
    float* out = (float*)d_out;

    // ws layout (4B words): cnt[200704] dinv[200704] row_ptr[200704]
    // bsum[1024] csr_src[ET] wt0+wt1[16384 words] hb[NT*DIM ushort]
    // total = 66.5 MB (R3-proven footprint, unchanged).
    // P[CH][NT] (25.6 MB) aliases hb (P dead after fillp_k);
    // x~1 (bf16 NT*DIM = 51.2 MB) also lives in hb, written by layer1
    // strictly after fillp_k consumed P.
    int* cnt = (int*)d_ws;
    float* dinv = (float*)(cnt + 200704);
    int* row_ptr = (int*)(dinv + 200704);
    int* bsum = row_ptr + 200704;
    int* csr_src = bsum + 1024;
    unsigned short* wt0 = (unsigned short*)(csr_src + ET);
    unsigned short* wt1 = wt0 + DIM * DIM;
    unsigned short* hb = wt1 + DIM * DIM;  // [NT*DIM] bf16
    int* P = (int*)hb;                     // [CH][NT] ints, dead before layer 1
    unsigned int* xq1 = (unsigned int*)hb; // x~1 packed, written by layer 1

    // output layout (floats): sr_seed | tg_seed | ent [NT, DIM]
    // x~0 (bf16, 51.2 MB) borrows the ent region's FIRST HALF: written by
    // convX2, read by layer1 (which writes x~1 to ws.hb — disjoint), dead
    // before layer2 overwrites the full ent region with final f32.
    float* sr_seed_out = out;
    float* tg_seed_out = out + (long long)NS * DIM;
    float* ent = out + (long long)2 * NS * DIM;
    unsigned int* xq0 = (unsigned int*)ent;

    const int gLayer = (NT + 63) / 64;     // 3125
    const int gConv = (NT * 64) / 256;     // 50000

    convW_k<<<(DIM * DIM + 255) / 256, 256, 0, stream>>>(W0, wt0);
    convW_k<<<(DIM * DIM + 255) / 256, 256, 0, stream>>>(W1, wt1);

    hist_k<<<NRANGE * CH, 1024, 0, stream>>>(edges_sr, edges_tg, P);
    reduceA_k<<<SB2, 256, 0, stream>>>(P, cnt, dinv, bsum);
    scanB_k<<<1, 1024, 0, stream>>>(bsum, row_ptr);
    scanCbase_k<<<SB2, 256, 0, stream>>>(cnt, bsum, row_ptr, P);
    fillp_k<<<NRANGE * CH, 1024, 0, stream>>>(edges_sr, edges_tg, P, csr_src);

    convX2_k<<<gConv, 256, 0, stream>>>(emb_sr, emb_tg, dinv, xq0);

    // layer 1: x~0 (ent half) -> x~1 (ws.hb), bf16 dinv-scaled
    layer_k<false><<<gLayer, 256, 0, stream>>>(row_ptr, csr_src, dinv, xq0, wt0,
                                               nullptr, (unsigned short*)xq1);
    // layer 2: x~1 (ws.hb) -> final f32 ent (overwrites dead x~0)
    layer_k<true><<<gLayer, 256, 0, stream>>>(row_ptr, csr_src, dinv, xq1, wt1,
                                              ent, nullptr);

    const int gSeed = (NS * 32 + 255) / 256;
    gather_k<<<gSeed, 256, 0, stream>>>(sr_seeds, ent, sr_seed_out, 0);
    gather_k<<<gSeed, 256, 0, stream>>>(tg_seeds, ent, tg_seed_out, NN);
}

// Round 5
// 590.306 us; speedup vs baseline: 1.4574x; 1.4574x over previous
//
#include <hip/hip_runtime.h>

#define NN 100000
#define NE 1600000
#define NT (2 * NN)        // combined nodes (sr | tg+NN)
#define ET (2 * NE)        // combined edges
#define DIM 128
#define NS 15000
#define SB2 ((NT + 255) / 256)  // 782 scan blocks
#define PAD 136                 // LDS row stride in bf16
#define NRANGE 8                // dst-range partition (1 range <-> 1 XCD)
#define RSZ (NT / NRANGE)       // 25000 nodes/range; LDS hist = 100 KB (<160 KB/CU)
#define CH 32                   // edge chunks
#define CI4 (ET / 4 / CH)       // 25000 i4-groups per chunk (exact)
#define NE4 (NE / 4)            // 400000

typedef __attribute__((ext_vector_type(8))) short frag_ab;  // 8 bf16
typedef __attribute__((ext_vector_type(4))) float frag_cd;  // 4 f32
typedef __attribute__((ext_vector_type(4))) int i4;

__device__ __forceinline__ unsigned short f2bf(float f) {  // RNE
    unsigned int u = __float_as_uint(f);
    u += 0x7fff + ((u >> 16) & 1);
    return (unsigned short)(u >> 16);
}
__device__ __forceinline__ float bflo(unsigned int u) { return __uint_as_float(u << 16); }
__device__ __forceinline__ float bfhi(unsigned int u) { return __uint_as_float(u & 0xffff0000u); }

// ---------------- pass 1: per-(range,chunk) LDS histogram -> P[c][node] ----------------
// Zero global atomics (round-3 proven: killed count_k's 112 MB atomic writeback).
__global__ __launch_bounds__(1024) void hist_k(const int* __restrict__ e_sr,
                                               const int* __restrict__ e_tg,
                                               int* __restrict__ P) {
    __shared__ int lc[RSZ];
    const int r = blockIdx.x & (NRANGE - 1);   // low bits -> XCD round-robin
    const int c = blockIdx.x >> 3;
    const int lo = r * RSZ;
    for (int i = threadIdx.x; i < RSZ; i += 1024) lc[i] = 0;
    __syncthreads();
    const int base = c * CI4;  // i4 units into the combined edge list
    for (int v = threadIdx.x; v < CI4; v += 1024) {
        i4 d4;
        if (c < 16) {
            d4 = *((const i4*)e_sr + NE4 + base + v);
        } else {
            d4 = *((const i4*)e_tg + base + v);
            d4 += NN;
        }
#pragma unroll
        for (int j = 0; j < 4; ++j) {
            const int t = d4[j] - lo;
            if ((unsigned)t < RSZ) atomicAdd(&lc[t], 1);
        }
    }
    __syncthreads();
    for (int i = threadIdx.x; i < RSZ; i += 1024) P[c * NT + lo + i] = lc[i];
}

// ---------------- cnt = sum_c P[c][n] ; fused dinv + scanA block sums ----------------
__global__ __launch_bounds__(256) void reduceA_k(const int* __restrict__ P,
                                                 int* __restrict__ cnt,
                                                 float* __restrict__ dinv,
                                                 int* __restrict__ bsum) {
    __shared__ int sh[256];
    const int t = threadIdx.x;
    const int i = blockIdx.x * 256 + t;
    int s = 0;
    if (i < NT) {
#pragma unroll
        for (int c = 0; c < CH; ++c) s += P[c * NT + i];
        cnt[i] = s;
        dinv[i] = rsqrtf((float)(s + 1));  // +1 self-loop
    }
    sh[t] = s;
    __syncthreads();
    for (int off = 128; off > 0; off >>= 1) {
        if (t < off) sh[t] += sh[t + off];
        __syncthreads();
    }
    if (t == 0) bsum[blockIdx.x] = sh[0];
}

__global__ __launch_bounds__(1024) void scanB_k(int* bsum, int* row_ptr) {
    __shared__ int s[1024];
    const int t = threadIdx.x;
    const int v = (t < SB2) ? bsum[t] : 0;
    s[t] = v;
    __syncthreads();
    for (int off = 1; off < 1024; off <<= 1) {
        int add = (t >= off) ? s[t - off] : 0;
        __syncthreads();
        s[t] += add;
        __syncthreads();
    }
    if (t < SB2) bsum[t] = s[t] - v;        // exclusive
    if (t == SB2 - 1) row_ptr[NT] = s[t];   // == ET
}

// ---------------- scanC + base fused: row_ptr + per-(chunk,node) slot bases ----------------
__global__ __launch_bounds__(256) void scanCbase_k(const int* __restrict__ cnt,
                                                   const int* __restrict__ bsum,
                                                   int* __restrict__ row_ptr,
                                                   int* __restrict__ P) {
    __shared__ int s[256];
    const int t = threadIdx.x;
    const int i = blockIdx.x * 256 + t;
    const int v = (i < NT) ? cnt[i] : 0;
    s[t] = v;
    __syncthreads();
    for (int off = 1; off < 256; off <<= 1) {
        int add = (t >= off) ? s[t - off] : 0;
        __syncthreads();
        s[t] += add;
        __syncthreads();
    }
    if (i < NT) {
        const int rp = bsum[blockIdx.x] + s[t] - v;
        row_ptr[i] = rp;
        int run = rp;
#pragma unroll
        for (int c = 0; c < CH; ++c) {
            const int pv = P[c * NT + i];
            P[c * NT + i] = run;
            run += pv;
        }
    }
}

// ---------------- pass 2: fill via LDS cursors, atomic-free globally ----------------
__global__ __launch_bounds__(1024) void fillp_k(const int* __restrict__ e_sr,
                                                const int* __restrict__ e_tg,
                                                const int* __restrict__ P,  // = base
                                                int* __restrict__ csr_src) {
    __shared__ int cur[RSZ];
    const int r = blockIdx.x & (NRANGE - 1);
    const int c = blockIdx.x >> 3;
    const int lo = r * RSZ;
    for (int i = threadIdx.x; i < RSZ; i += 1024) cur[i] = P[c * NT + lo + i];
    __syncthreads();
    const int base = c * CI4;
    for (int v = threadIdx.x; v < CI4; v += 1024) {
        i4 s4, d4;
        if (c < 16) {
            s4 = *((const i4*)e_sr + base + v);
            d4 = *((const i4*)e_sr + NE4 + base + v);
        } else {
            s4 = *((const i4*)e_tg + base + v - NE4);
            d4 = *((const i4*)e_tg + base + v);
            s4 += NN;
            d4 += NN;
        }
#pragma unroll
        for (int j = 0; j < 4; ++j) {
            const int t = d4[j] - lo;
            if ((unsigned)t < RSZ) {
                const int pos = atomicAdd(&cur[t], 1);
                csr_src[pos] = s4[j];  // plain store: L2-resident slice per range
            }
        }
    }
}

// Wt[n][k] = bf16(W[k][n]), both weights in one dispatch
__global__ __launch_bounds__(256) void convW2_k(const float* __restrict__ W0,
                                                const float* __restrict__ W1,
                                                unsigned short* __restrict__ wt0,
                                                unsigned short* __restrict__ wt1) {
    int i = blockIdx.x * 256 + threadIdx.x;
    if (i >= 2 * DIM * DIM) return;
    const float* W = (i < DIM * DIM) ? W0 : W1;
    unsigned short* wt = (i < DIM * DIM) ? wt0 : wt1;
    const int ii = i & (DIM * DIM - 1);
    const int n = ii & 127, k = ii >> 7;
    wt[n * DIM + k] = f2bf(W[k * DIM + n]);
}

// ---------------- layer-1 GEMM with fused f32->bf16 staging ----------------
// Gb = dinv ⊙ (bf16(emb) @ W0).  Reads the f32 embeddings directly (conversion
// during LDS staging) — deletes the convX pass (102 MB read + 51 MB write).
__global__ __launch_bounds__(256) void gemmE_k(const float* __restrict__ emb_sr,
                                               const float* __restrict__ emb_tg,
                                               const unsigned short* __restrict__ Wt,
                                               const float* __restrict__ dinv,
                                               unsigned short* __restrict__ Gb) {
    __shared__ unsigned short xs[64 * PAD];   // 17.4 KB
    __shared__ unsigned short ws[128 * PAD];  // 34.8 KB
    const int tid = threadIdx.x;
    const int row0 = blockIdx.x * 64;         // NT % 64 == 0: no clamp needed

    for (int i = tid; i < 128 * 16; i += 256) {
        const int r = i >> 4, o = i & 15;
        *(uint4*)&ws[r * PAD + o * 8] = *(const uint4*)&Wt[r * DIM + o * 8];
    }
    for (int i = tid; i < 64 * 32; i += 256) {  // 64 rows x 32 float4
        const int r = i >> 5, o = i & 31;
        const int gr = row0 + r;
        const float4 v = (gr < NN) ? ((const float4*)emb_sr)[gr * 32 + o]
                                   : ((const float4*)emb_tg)[(gr - NN) * 32 + o];
        ushort4 b;
        b.x = f2bf(v.x); b.y = f2bf(v.y); b.z = f2bf(v.z); b.w = f2bf(v.w);
        *(ushort4*)&xs[r * PAD + o * 4] = b;
    }
    __syncthreads();

    const int wave = tid >> 6;
    const int lane = tid & 63;
    const int m = lane & 15;
    const int quad = lane >> 4;
    const int rbase = wave * 16;

    frag_cd acc[8];
#pragma unroll
    for (int ct = 0; ct < 8; ct++) acc[ct] = (frag_cd){0.f, 0.f, 0.f, 0.f};

#pragma unroll
    for (int ks = 0; ks < 4; ks++) {
        const frag_ab a = *(const frag_ab*)&xs[(rbase + m) * PAD + ks * 32 + quad * 8];
#pragma unroll
        for (int ct = 0; ct < 8; ct++) {
            const frag_ab b = *(const frag_ab*)&ws[(ct * 16 + m) * PAD + ks * 32 + quad * 8];
            acc[ct] = __builtin_amdgcn_mfma_f32_16x16x32_bf16(a, b, acc[ct], 0, 0, 0);
        }
    }

    // C/D layout: col = lane&15, row = quad*4 + reg
#pragma unroll
    for (int r = 0; r < 4; r++) {
        const int grow = row0 + rbase + quad * 4 + r;
        const float dv = dinv[grow];
#pragma unroll
        for (int ct = 0; ct < 8; ct++)
            Gb[grow * DIM + ct * 16 + m] = f2bf(dv * acc[ct][r]);
    }
}

// ---------------- layer-2 GEMM (bf16 input): Gb = dinv ⊙ (Xb @ W) ----------------
__global__ __launch_bounds__(256) void gemm_mfma_k(const unsigned short* __restrict__ Xb,
                                                   const unsigned short* __restrict__ Wt,
                                                   const float* __restrict__ dinv,
                                                   unsigned short* __restrict__ Gb) {
    __shared__ unsigned short xs[64 * PAD];   // 17.4 KB
    __shared__ unsigned short ws[128 * PAD];  // 34.8 KB
    const int tid = threadIdx.x;
    const int row0 = blockIdx.x * 64;

    for (int i = tid; i < 128 * 16; i += 256) {
        const int r = i >> 4, o = i & 15;
        *(uint4*)&ws[r * PAD + o * 8] = *(const uint4*)&Wt[r * DIM + o * 8];
    }
    for (int i = tid; i < 64 * 16; i += 256) {
        const int r = i >> 4, o = i & 15;
        *(uint4*)&xs[r * PAD + o * 8] = *(const uint4*)&Xb[(row0 + r) * DIM + o * 8];
    }
    __syncthreads();

    const int wave = tid >> 6;
    const int lane = tid & 63;
    const int m = lane & 15;
    const int quad = lane >> 4;
    const int rbase = wave * 16;

    frag_cd acc[8];
#pragma unroll
    for (int ct = 0; ct < 8; ct++) acc[ct] = (frag_cd){0.f, 0.f, 0.f, 0.f};

#pragma unroll
    for (int ks = 0; ks < 4; ks++) {
        const frag_ab a = *(const frag_ab*)&xs[(rbase + m) * PAD + ks * 32 + quad * 8];
#pragma unroll
        for (int ct = 0; ct < 8; ct++) {
            const frag_ab b = *(const frag_ab*)&ws[(ct * 16 + m) * PAD + ks * 32 + quad * 8];
            acc[ct] = __builtin_amdgcn_mfma_f32_16x16x32_bf16(a, b, acc[ct], 0, 0, 0);
        }
    }

#pragma unroll
    for (int r = 0; r < 4; r++) {
        const int grow = row0 + rbase + quad * 4 + r;
        const float dv = dinv[grow];
#pragma unroll
        for (int ct = 0; ct < 8; ct++)
            Gb[grow * DIM + ct * 16 + m] = f2bf(dv * acc[ct][r]);
    }
}

// ---------------- fused pull (weightless gather) + residual + ReLU ----------------
// out[t] = relu( dinv[t]*(g[t] + Σ g[src]) + g[t]*sqrt(deg[t]) )
// One wave per node (round-3 structure: 200K independent waves = the MLP that
// round 4's fused layer destroyed). 8-deep unroll for latency depth.
template <bool OUT_BF16>
__global__ __launch_bounds__(256) void pull_k(const int* __restrict__ row_ptr,
                                              const int* __restrict__ csr_src,
                                              const float* __restrict__ dinv,
                                              const unsigned short* __restrict__ Gb,
                                              float* __restrict__ outf,
                                              unsigned short* __restrict__ outb) {
    const int node = (blockIdx.x * 256 + threadIdx.x) >> 6;
    if (node >= NT) return;
    const int lane = threadIdx.x & 63;
    const unsigned int* __restrict__ G2 = (const unsigned int*)Gb;

    const int beg = row_ptr[node];
    const int end = row_ptr[node + 1];
    const float d = dinv[node];
    const float sq = 1.0f / d;  // sqrt(deg)

    const unsigned int gu = G2[node * 64 + lane];
    float sx = bflo(gu);  // self-loop term g[t]
    float sy = bfhi(gu);
    const float hx = sx * sq;  // residual h[t] = g[t]*sqrt(deg)
    const float hy = sy * sq;

    for (int base = beg; base < end; base += 64) {
        int rem = end - base; if (rem > 64) rem = 64;
        const int sl = (lane < rem) ? csr_src[base + lane] : 0;
        int j = 0;
        for (; j + 8 <= rem; j += 8) {
            const int s0 = __shfl(sl, j + 0);
            const int s1 = __shfl(sl, j + 1);
            const int s2 = __shfl(sl, j + 2);
            const int s3 = __shfl(sl, j + 3);
            const int s4 = __shfl(sl, j + 4);
            const int s5 = __shfl(sl, j + 5);
            const int s6 = __shfl(sl, j + 6);
            const int s7 = __shfl(sl, j + 7);
            const unsigned int m0 = G2[s0 * 64 + lane];
            const unsigned int m1 = G2[s1 * 64 + lane];
            const unsigned int m2 = G2[s2 * 64 + lane];
            const unsigned int m3 = G2[s3 * 64 + lane];
            const unsigned int m4 = G2[s4 * 64 + lane];
            const unsigned int m5 = G2[s5 * 64 + lane];
            const unsigned int m6 = G2[s6 * 64 + lane];
            const unsigned int m7 = G2[s7 * 64 + lane];
            sx += bflo(m0) + bflo(m1) + bflo(m2) + bflo(m3)
                + bflo(m4) + bflo(m5) + bflo(m6) + bflo(m7);
            sy += bfhi(m0) + bfhi(m1) + bfhi(m2) + bfhi(m3)
                + bfhi(m4) + bfhi(m5) + bfhi(m6) + bfhi(m7);
        }
        for (; j < rem; ++j) {
            const int s = __shfl(sl, j);
            const unsigned int mu = G2[s * 64 + lane];
            sx += bflo(mu);
            sy += bfhi(mu);
        }
    }
    const float ax = fmaxf(d * sx + hx, 0.f);
    const float ay = fmaxf(d * sy + hy, 0.f);
    if (OUT_BF16) {
        ((unsigned int*)outb)[node * 64 + lane] =
            (unsigned int)f2bf(ax) | ((unsigned int)f2bf(ay) << 16);
    } else {
        float2 o; o.x = ax; o.y = ay;
        ((float2*)outf)[node * 64 + lane] = o;
    }
}

// ---------------- seed gather ----------------
__global__ __launch_bounds__(256) void gather_k(const int* __restrict__ seeds,
                                                const float* __restrict__ ent,
                                                float* __restrict__ out, int node_off) {
    const int gid = blockIdx.x * 256 + threadIdx.x;
    const int s = gid >> 5;
    if (s >= NS) return;
    const int q = gid & 31;
    ((float4*)out)[s * 32 + q] =
        ((const float4*)ent)[(seeds[s] + node_off) * 32 + q];
}

extern "C" void kernel_launch(void* const* d_in, const int* in_sizes, int n_in,
                              void* d_out, int out_size, void* d_ws, size_t ws_size,
                              hipStream_t stream) {
    const int* sr_seeds = (const int*)d_in[0];
    const int* tg_seeds = (const int*)d_in[1];
    const int* edges_sr = (const int*)d_in[2];
    const int* edges_tg = (const int*)d_in[3];
    const float* emb_sr = (const float*)d_in[4];
    const float* emb_tg = (const float*)d_in[5];
    const float* W0 = (const float*)d_in[6];
    const float* W1 = (const float*)d_in[7];
    float* out = (float*)d_out;

    // ws layout (4B words): cnt[200704] dinv[200704] row_ptr[200704]
    // bsum[1024] csr_src[ET] wt0+wt1[16384 words] hb[NT*DIM ushort]
    // total = 66.5 MB (R3-proven footprint, unchanged).
    // P[CH][NT] (25.6 MB) aliases hb; dead before gemmE writes hb.
    int* cnt = (int*)d_ws;
    float* dinv = (float*)(cnt + 200704);
    int* row_ptr = (int*)(dinv + 200704);
    int* bsum = row_ptr + 200704;
    int* csr_src = bsum + 1024;
    unsigned short* wt0 = (unsigned short*)(csr_src + ET);
    unsigned short* wt1 = wt0 + DIM * DIM;
    unsigned short* hb = wt1 + DIM * DIM;  // [NT*DIM] bf16 (g buffer)
    int* P = (int*)hb;                     // [CH][NT] ints, dead before gemmE

    // output layout (floats): sr_seed | tg_seed | ent [NT, DIM]
    // x1 (bf16) borrows the ent region: written by pull<true>, consumed by
    // layer-2 gemm before pull<false> overwrites the region with final f32.
    float* sr_seed_out = out;
    float* tg_seed_out = out + (long long)NS * DIM;
    float* ent = out + (long long)2 * NS * DIM;
    unsigned short* xb = (unsigned short*)ent;

    const int gGemm = (NT + 63) / 64;      // 3125
    const int gPull = NT / 4;              // 50000

    convW2_k<<<(2 * DIM * DIM + 255) / 256, 256, 0, stream>>>(W0, W1, wt0, wt1);

    hist_k<<<NRANGE * CH, 1024, 0, stream>>>(edges_sr, edges_tg, P);
    reduceA_k<<<SB2, 256, 0, stream>>>(P, cnt, dinv, bsum);
    scanB_k<<<1, 1024, 0, stream>>>(bsum, row_ptr);
    scanCbase_k<<<SB2, 256, 0, stream>>>(cnt, bsum, row_ptr, P);
    fillp_k<<<NRANGE * CH, 1024, 0, stream>>>(edges_sr, edges_tg, P, csr_src);

    // layer 1: g1 = dinv ⊙ (bf16(emb)@W0) -> hb (conversion fused into staging)
    gemmE_k<<<gGemm, 256, 0, stream>>>(emb_sr, emb_tg, wt0, dinv, hb);
    pull_k<true><<<gPull, 256, 0, stream>>>(row_ptr, csr_src, dinv, hb, nullptr, xb);
    // layer 2: g2 = dinv ⊙ (x1@W1) -> hb ; ent(f32) overwrites x1's region
    gemm_mfma_k<<<gGemm, 256, 0, stream>>>(xb, wt1, dinv, hb);
    pull_k<false><<<gPull, 256, 0, stream>>>(row_ptr, csr_src, dinv, hb, ent, nullptr);

    const int gSeed = (NS * 32 + 255) / 256;
    gather_k<<<gSeed, 256, 0, stream>>>(sr_seeds, ent, sr_seed_out, 0);
    gather_k<<<gSeed, 256, 0, stream>>>(tg_seeds, ent, tg_seed_out, NN);
}

// Round 6
// 579.180 us; speedup vs baseline: 1.4854x; 1.0192x over previous
//
#include <hip/hip_runtime.h>

#define NN 100000
#define NE 1600000
#define NT (2 * NN)        // combined nodes (sr | tg+NN)
#define ET (2 * NE)        // combined edges
#define DIM 128
#define NS 15000
#define SB2 ((NT + 255) / 256)  // 782 scan blocks
#define PAD 136                 // LDS row stride in bf16
#define NRANGE 8                // dst-range partition (1 range <-> 1 XCD)
#define RSZ (NT / NRANGE)       // 25000 nodes/range; LDS hist = 100 KB (<160 KB/CU)
#define CH 32                   // edge chunks
#define CI4 (ET / 4 / CH)       // 25000 i4-groups per chunk (exact)
#define NE4 (NE / 4)            // 400000

typedef __attribute__((ext_vector_type(8))) short frag_ab;  // 8 bf16
typedef __attribute__((ext_vector_type(4))) float frag_cd;  // 4 f32
typedef __attribute__((ext_vector_type(4))) int i4;

__device__ __forceinline__ unsigned short f2bf(float f) {  // RNE
    unsigned int u = __float_as_uint(f);
    u += 0x7fff + ((u >> 16) & 1);
    return (unsigned short)(u >> 16);
}
__device__ __forceinline__ float bflo(unsigned int u) { return __uint_as_float(u << 16); }
__device__ __forceinline__ float bfhi(unsigned int u) { return __uint_as_float(u & 0xffff0000u); }

// ---------------- pass 1: per-(range,chunk) LDS histogram -> P[c][node] ----------------
// Zero global atomics (round-3 proven: killed count_k's 112 MB atomic writeback).
__global__ __launch_bounds__(1024) void hist_k(const int* __restrict__ e_sr,
                                               const int* __restrict__ e_tg,
                                               int* __restrict__ P) {
    __shared__ int lc[RSZ];
    const int r = blockIdx.x & (NRANGE - 1);   // low bits -> XCD round-robin
    const int c = blockIdx.x >> 3;
    const int lo = r * RSZ;
    for (int i = threadIdx.x; i < RSZ; i += 1024) lc[i] = 0;
    __syncthreads();
    const int base = c * CI4;  // i4 units into the combined edge list
    for (int v = threadIdx.x; v < CI4; v += 1024) {
        i4 d4;
        if (c < 16) {
            d4 = *((const i4*)e_sr + NE4 + base + v);
        } else {
            d4 = *((const i4*)e_tg + base + v);
            d4 += NN;
        }
#pragma unroll
        for (int j = 0; j < 4; ++j) {
            const int t = d4[j] - lo;
            if ((unsigned)t < RSZ) atomicAdd(&lc[t], 1);
        }
    }
    __syncthreads();
    for (int i = threadIdx.x; i < RSZ; i += 1024) P[c * NT + lo + i] = lc[i];
}

// ---------------- cnt = sum_c P[c][n] ; fused dinv + scanA block sums ----------------
__global__ __launch_bounds__(256) void reduceA_k(const int* __restrict__ P,
                                                 int* __restrict__ cnt,
                                                 float* __restrict__ dinv,
                                                 int* __restrict__ bsum) {
    __shared__ int sh[256];
    const int t = threadIdx.x;
    const int i = blockIdx.x * 256 + t;
    int s = 0;
    if (i < NT) {
#pragma unroll
        for (int c = 0; c < CH; ++c) s += P[c * NT + i];
        cnt[i] = s;
        dinv[i] = rsqrtf((float)(s + 1));  // +1 self-loop
    }
    sh[t] = s;
    __syncthreads();
    for (int off = 128; off > 0; off >>= 1) {
        if (t < off) sh[t] += sh[t + off];
        __syncthreads();
    }
    if (t == 0) bsum[blockIdx.x] = sh[0];
}

__global__ __launch_bounds__(1024) void scanB_k(int* bsum, int* row_ptr) {
    __shared__ int s[1024];
    const int t = threadIdx.x;
    const int v = (t < SB2) ? bsum[t] : 0;
    s[t] = v;
    __syncthreads();
    for (int off = 1; off < 1024; off <<= 1) {
        int add = (t >= off) ? s[t - off] : 0;
        __syncthreads();
        s[t] += add;
        __syncthreads();
    }
    if (t < SB2) bsum[t] = s[t] - v;        // exclusive
    if (t == SB2 - 1) row_ptr[NT] = s[t];   // == ET
}

// ---------------- scanC + base fused: row_ptr + per-(chunk,node) slot bases ----------------
__global__ __launch_bounds__(256) void scanCbase_k(const int* __restrict__ cnt,
                                                   const int* __restrict__ bsum,
                                                   int* __restrict__ row_ptr,
                                                   int* __restrict__ P) {
    __shared__ int s[256];
    const int t = threadIdx.x;
    const int i = blockIdx.x * 256 + t;
    const int v = (i < NT) ? cnt[i] : 0;
    s[t] = v;
    __syncthreads();
    for (int off = 1; off < 256; off <<= 1) {
        int add = (t >= off) ? s[t - off] : 0;
        __syncthreads();
        s[t] += add;
        __syncthreads();
    }
    if (i < NT) {
        const int rp = bsum[blockIdx.x] + s[t] - v;
        row_ptr[i] = rp;
        int run = rp;
#pragma unroll
        for (int c = 0; c < CH; ++c) {
            const int pv = P[c * NT + i];
            P[c * NT + i] = run;
            run += pv;
        }
    }
}

// ---------------- pass 2: fill via LDS cursors, atomic-free globally ----------------
__global__ __launch_bounds__(1024) void fillp_k(const int* __restrict__ e_sr,
                                                const int* __restrict__ e_tg,
                                                const int* __restrict__ P,  // = base
                                                int* __restrict__ csr_src) {
    __shared__ int cur[RSZ];
    const int r = blockIdx.x & (NRANGE - 1);
    const int c = blockIdx.x >> 3;
    const int lo = r * RSZ;
    for (int i = threadIdx.x; i < RSZ; i += 1024) cur[i] = P[c * NT + lo + i];
    __syncthreads();
    const int base = c * CI4;
    for (int v = threadIdx.x; v < CI4; v += 1024) {
        i4 s4, d4;
        if (c < 16) {
            s4 = *((const i4*)e_sr + base + v);
            d4 = *((const i4*)e_sr + NE4 + base + v);
        } else {
            s4 = *((const i4*)e_tg + base + v - NE4);
            d4 = *((const i4*)e_tg + base + v);
            s4 += NN;
            d4 += NN;
        }
#pragma unroll
        for (int j = 0; j < 4; ++j) {
            const int t = d4[j] - lo;
            if ((unsigned)t < RSZ) {
                const int pos = atomicAdd(&cur[t], 1);
                csr_src[pos] = s4[j];  // plain store: L2-resident slice per range
            }
        }
    }
}

// Wt[n][k] = bf16(W[k][n]), both weights in one dispatch
__global__ __launch_bounds__(256) void convW2_k(const float* __restrict__ W0,
                                                const float* __restrict__ W1,
                                                unsigned short* __restrict__ wt0,
                                                unsigned short* __restrict__ wt1) {
    int i = blockIdx.x * 256 + threadIdx.x;
    if (i >= 2 * DIM * DIM) return;
    const float* W = (i < DIM * DIM) ? W0 : W1;
    unsigned short* wt = (i < DIM * DIM) ? wt0 : wt1;
    const int ii = i & (DIM * DIM - 1);
    const int n = ii & 127, k = ii >> 7;
    wt[n * DIM + k] = f2bf(W[k * DIM + n]);
}

// ---------------- layer-1 GEMM with fused f32->bf16 staging ----------------
// Gb = dinv ⊙ (bf16(emb) @ W0).  Reads the f32 embeddings directly (conversion
// during LDS staging) — deletes the convX pass (102 MB read + 51 MB write).
__global__ __launch_bounds__(256) void gemmE_k(const float* __restrict__ emb_sr,
                                               const float* __restrict__ emb_tg,
                                               const unsigned short* __restrict__ Wt,
                                               const float* __restrict__ dinv,
                                               unsigned short* __restrict__ Gb) {
    __shared__ unsigned short xs[64 * PAD];   // 17.4 KB
    __shared__ unsigned short ws[128 * PAD];  // 34.8 KB
    const int tid = threadIdx.x;
    const int row0 = blockIdx.x * 64;         // NT % 64 == 0: no clamp needed

    for (int i = tid; i < 128 * 16; i += 256) {
        const int r = i >> 4, o = i & 15;
        *(uint4*)&ws[r * PAD + o * 8] = *(const uint4*)&Wt[r * DIM + o * 8];
    }
    for (int i = tid; i < 64 * 32; i += 256) {  // 64 rows x 32 float4
        const int r = i >> 5, o = i & 31;
        const int gr = row0 + r;
        const float4 v = (gr < NN) ? ((const float4*)emb_sr)[gr * 32 + o]
                                   : ((const float4*)emb_tg)[(gr - NN) * 32 + o];
        ushort4 b;
        b.x = f2bf(v.x); b.y = f2bf(v.y); b.z = f2bf(v.z); b.w = f2bf(v.w);
        *(ushort4*)&xs[r * PAD + o * 4] = b;
    }
    __syncthreads();

    const int wave = tid >> 6;
    const int lane = tid & 63;
    const int m = lane & 15;
    const int quad = lane >> 4;
    const int rbase = wave * 16;

    frag_cd acc[8];
#pragma unroll
    for (int ct = 0; ct < 8; ct++) acc[ct] = (frag_cd){0.f, 0.f, 0.f, 0.f};

#pragma unroll
    for (int ks = 0; ks < 4; ks++) {
        const frag_ab a = *(const frag_ab*)&xs[(rbase + m) * PAD + ks * 32 + quad * 8];
#pragma unroll
        for (int ct = 0; ct < 8; ct++) {
            const frag_ab b = *(const frag_ab*)&ws[(ct * 16 + m) * PAD + ks * 32 + quad * 8];
            acc[ct] = __builtin_amdgcn_mfma_f32_16x16x32_bf16(a, b, acc[ct], 0, 0, 0);
        }
    }

    // C/D layout: col = lane&15, row = quad*4 + reg
#pragma unroll
    for (int r = 0; r < 4; r++) {
        const int grow = row0 + rbase + quad * 4 + r;
        const float dv = dinv[grow];
#pragma unroll
        for (int ct = 0; ct < 8; ct++)
            Gb[grow * DIM + ct * 16 + m] = f2bf(dv * acc[ct][r]);
    }
}

// ---------------- layer-2 GEMM (bf16 input): Gb = dinv ⊙ (Xb @ W) ----------------
__global__ __launch_bounds__(256) void gemm_mfma_k(const unsigned short* __restrict__ Xb,
                                                   const unsigned short* __restrict__ Wt,
                                                   const float* __restrict__ dinv,
                                                   unsigned short* __restrict__ Gb) {
    __shared__ unsigned short xs[64 * PAD];   // 17.4 KB
    __shared__ unsigned short ws[128 * PAD];  // 34.8 KB
    const int tid = threadIdx.x;
    const int row0 = blockIdx.x * 64;

    for (int i = tid; i < 128 * 16; i += 256) {
        const int r = i >> 4, o = i & 15;
        *(uint4*)&ws[r * PAD + o * 8] = *(const uint4*)&Wt[r * DIM + o * 8];
    }
    for (int i = tid; i < 64 * 16; i += 256) {
        const int r = i >> 4, o = i & 15;
        *(uint4*)&xs[r * PAD + o * 8] = *(const uint4*)&Xb[(row0 + r) * DIM + o * 8];
    }
    __syncthreads();

    const int wave = tid >> 6;
    const int lane = tid & 63;
    const int m = lane & 15;
    const int quad = lane >> 4;
    const int rbase = wave * 16;

    frag_cd acc[8];
#pragma unroll
    for (int ct = 0; ct < 8; ct++) acc[ct] = (frag_cd){0.f, 0.f, 0.f, 0.f};

#pragma unroll
    for (int ks = 0; ks < 4; ks++) {
        const frag_ab a = *(const frag_ab*)&xs[(rbase + m) * PAD + ks * 32 + quad * 8];
#pragma unroll
        for (int ct = 0; ct < 8; ct++) {
            const frag_ab b = *(const frag_ab*)&ws[(ct * 16 + m) * PAD + ks * 32 + quad * 8];
            acc[ct] = __builtin_amdgcn_mfma_f32_16x16x32_bf16(a, b, acc[ct], 0, 0, 0);
        }
    }

#pragma unroll
    for (int r = 0; r < 4; r++) {
        const int grow = row0 + rbase + quad * 4 + r;
        const float dv = dinv[grow];
#pragma unroll
        for (int ct = 0; ct < 8; ct++)
            Gb[grow * DIM + ct * 16 + m] = f2bf(dv * acc[ct][r]);
    }
}

// ---------------- fused pull (weightless gather) + residual + ReLU ----------------
// out[t] = relu( dinv[t]*(g[t] + Σ g[src]) + g[t]*sqrt(deg[t]) )
// One wave per node. 16-deep primary gather batch: avg degree = 16, so the
// whole typical node is issued before the first dependent sum (R5 evidence:
// BW scales linearly with concurrency -> latency-bound, not a fabric floor).
template <bool OUT_BF16>
__global__ __launch_bounds__(256) void pull_k(const int* __restrict__ row_ptr,
                                              const int* __restrict__ csr_src,
                                              const float* __restrict__ dinv,
                                              const unsigned short* __restrict__ Gb,
                                              float* __restrict__ outf,
                                              unsigned short* __restrict__ outb) {
    const int node = (blockIdx.x * 256 + threadIdx.x) >> 6;
    if (node >= NT) return;
    const int lane = threadIdx.x & 63;
    const unsigned int* __restrict__ G2 = (const unsigned int*)Gb;

    const int beg = row_ptr[node];
    const int end = row_ptr[node + 1];
    const float d = dinv[node];
    const float sq = 1.0f / d;  // sqrt(deg)

    const unsigned int gu = G2[node * 64 + lane];
    float sx = bflo(gu);  // self-loop term g[t]
    float sy = bfhi(gu);
    const float hx = sx * sq;  // residual h[t] = g[t]*sqrt(deg)
    const float hy = sy * sq;

    for (int base = beg; base < end; base += 64) {
        int rem = end - base; if (rem > 64) rem = 64;
        const int sl = (lane < rem) ? csr_src[base + lane] : 0;
        int j = 0;
        for (; j + 16 <= rem; j += 16) {  // 16 outstanding gathers
            int ss[16];
            unsigned int mm[16];
#pragma unroll
            for (int q = 0; q < 16; ++q) ss[q] = __shfl(sl, j + q);
#pragma unroll
            for (int q = 0; q < 16; ++q) mm[q] = G2[ss[q] * 64 + lane];
#pragma unroll
            for (int q = 0; q < 16; ++q) { sx += bflo(mm[q]); sy += bfhi(mm[q]); }
        }
        for (; j + 8 <= rem; j += 8) {
            int ss[8];
            unsigned int mm[8];
#pragma unroll
            for (int q = 0; q < 8; ++q) ss[q] = __shfl(sl, j + q);
#pragma unroll
            for (int q = 0; q < 8; ++q) mm[q] = G2[ss[q] * 64 + lane];
#pragma unroll
            for (int q = 0; q < 8; ++q) { sx += bflo(mm[q]); sy += bfhi(mm[q]); }
        }
        for (; j + 4 <= rem; j += 4) {
            int ss[4];
            unsigned int mm[4];
#pragma unroll
            for (int q = 0; q < 4; ++q) ss[q] = __shfl(sl, j + q);
#pragma unroll
            for (int q = 0; q < 4; ++q) mm[q] = G2[ss[q] * 64 + lane];
#pragma unroll
            for (int q = 0; q < 4; ++q) { sx += bflo(mm[q]); sy += bfhi(mm[q]); }
        }
        for (; j < rem; ++j) {
            const int s = __shfl(sl, j);
            const unsigned int mu = G2[s * 64 + lane];
            sx += bflo(mu);
            sy += bfhi(mu);
        }
    }
    const float ax = fmaxf(d * sx + hx, 0.f);
    const float ay = fmaxf(d * sy + hy, 0.f);
    if (OUT_BF16) {
        ((unsigned int*)outb)[node * 64 + lane] =
            (unsigned int)f2bf(ax) | ((unsigned int)f2bf(ay) << 16);
    } else {
        float2 o; o.x = ax; o.y = ay;
        ((float2*)outf)[node * 64 + lane] = o;
    }
}

// ---------------- seed gather (both seed sets in one dispatch) ----------------
__global__ __launch_bounds__(256) void gather2_k(const int* __restrict__ sr_seeds,
                                                 const int* __restrict__ tg_seeds,
                                                 const float* __restrict__ ent,
                                                 float* __restrict__ sr_out,
                                                 float* __restrict__ tg_out) {
    const int gid = blockIdx.x * 256 + threadIdx.x;
    const int s = gid >> 5;
    if (s >= 2 * NS) return;
    const int q = gid & 31;
    const bool tg = s >= NS;
    const int si = tg ? s - NS : s;
    const int node = tg ? tg_seeds[si] + NN : sr_seeds[si];
    float* o = tg ? tg_out : sr_out;
    ((float4*)o)[si * 32 + q] = ((const float4*)ent)[node * 32 + q];
}

extern "C" void kernel_launch(void* const* d_in, const int* in_sizes, int n_in,
                              void* d_out, int out_size, void* d_ws, size_t ws_size,
                              hipStream_t stream) {
    const int* sr_seeds = (const int*)d_in[0];
    const int* tg_seeds = (const int*)d_in[1];
    const int* edges_sr = (const int*)d_in[2];
    const int* edges_tg = (const int*)d_in[3];
    const float* emb_sr = (const float*)d_in[4];
    const float* emb_tg = (const float*)d_in[5];
    const float* W0 = (const float*)d_in[6];
    const float* W1 = (const float*)d_in[7];
    float* out = (float*)d_out;

    // ws layout (4B words): cnt[200704] dinv[200704] row_ptr[200704]
    // bsum[1024] csr_src[ET] wt0+wt1[16384 words] hb[NT*DIM ushort]
    // total = 66.5 MB (R3-proven footprint, unchanged).
    // P[CH][NT] (25.6 MB) aliases hb; dead before gemmE writes hb.
    int* cnt = (int*)d_ws;
    float* dinv = (float*)(cnt + 200704);
    int* row_ptr = (int*)(dinv + 200704);
    int* bsum = row_ptr + 200704;
    int* csr_src = bsum + 1024;
    unsigned short* wt0 = (unsigned short*)(csr_src + ET);
    unsigned short* wt1 = wt0 + DIM * DIM;
    unsigned short* hb = wt1 + DIM * DIM;  // [NT*DIM] bf16 (g buffer)
    int* P = (int*)hb;                     // [CH][NT] ints, dead before gemmE

    // output layout (floats): sr_seed | tg_seed | ent [NT, DIM]
    // x1 (bf16) borrows the ent region: written by pull<true>, consumed by
    // layer-2 gemm before pull<false> overwrites the region with final f32.
    float* sr_seed_out = out;
    float* tg_seed_out = out + (long long)NS * DIM;
    float* ent = out + (long long)2 * NS * DIM;
    unsigned short* xb = (unsigned short*)ent;

    const int gGemm = (NT + 63) / 64;      // 3125
    const int gPull = NT / 4;              // 50000

    convW2_k<<<(2 * DIM * DIM + 255) / 256, 256, 0, stream>>>(W0, W1, wt0, wt1);

    hist_k<<<NRANGE * CH, 1024, 0, stream>>>(edges_sr, edges_tg, P);
    reduceA_k<<<SB2, 256, 0, stream>>>(P, cnt, dinv, bsum);
    scanB_k<<<1, 1024, 0, stream>>>(bsum, row_ptr);
    scanCbase_k<<<SB2, 256, 0, stream>>>(cnt, bsum, row_ptr, P);
    fillp_k<<<NRANGE * CH, 1024, 0, stream>>>(edges_sr, edges_tg, P, csr_src);

    // layer 1: g1 = dinv ⊙ (bf16(emb)@W0) -> hb (conversion fused into staging)
    gemmE_k<<<gGemm, 256, 0, stream>>>(emb_sr, emb_tg, wt0, dinv, hb);
    pull_k<true><<<gPull, 256, 0, stream>>>(row_ptr, csr_src, dinv, hb, nullptr, xb);
    // layer 2: g2 = dinv ⊙ (x1@W1) -> hb ; ent(f32) overwrites x1's region
    gemm_mfma_k<<<gGemm, 256, 0, stream>>>(xb, wt1, dinv, hb);
    pull_k<false><<<gPull, 256, 0, stream>>>(row_ptr, csr_src, dinv, hb, ent, nullptr);

    const int gSeed = (2 * NS * 32 + 255) / 256;
    gather2_k<<<gSeed, 256, 0, stream>>>(sr_seeds, tg_seeds, ent, sr_seed_out, tg_seed_out);
}

// Round 7
// 564.480 us; speedup vs baseline: 1.5241x; 1.0260x over previous
//
#include <hip/hip_runtime.h>

#define NN 100000
#define NE 1600000
#define NT (2 * NN)        // combined nodes (sr | tg+NN)
#define ET (2 * NE)        // combined edges
#define DIM 128
#define NS 15000
#define SB2 ((NT + 255) / 256)  // 782 scan blocks
#define PAD 136                 // LDS row stride in bf16
#define NRANGE 16               // dst-range partition
#define RSZ (NT / NRANGE)       // 12500 nodes/range; LDS hist = 50 KB
#define CH 16                   // sub-chunks per range (rank structure)
#define BCAP 210000             // per-range bucket capacity (E=200K, sigma~433: 23 sigma)
#define NE4 (NE / 4)            // 400000

typedef __attribute__((ext_vector_type(8))) short frag_ab;  // 8 bf16
typedef __attribute__((ext_vector_type(4))) float frag_cd;  // 4 f32
typedef __attribute__((ext_vector_type(4))) int i4;

__device__ __forceinline__ unsigned short f2bf(float f) {  // RNE
    unsigned int u = __float_as_uint(f);
    u += 0x7fff + ((u >> 16) & 1);
    return (unsigned short)(u >> 16);
}
__device__ __forceinline__ float bflo(unsigned int u) { return __uint_as_float(u << 16); }
__device__ __forceinline__ float bfhi(unsigned int u) { return __uint_as_float(u & 0xffff0000u); }

// ---------------- bucket pass: partition edges by dst-range, ONCE ----------------
// Replaces the x8/x16 edge re-reads of the old hist/fillp (307 MB -> 38 MB).
// Packed word: (dst_local << 18) | src_global   (14 + 18 = 32 bits exactly).
// Per-wave LDS counters avoid same-address atomic serialization; one global
// atomicAdd per (block, range) reserves exact space — buckets are dense.
__global__ __launch_bounds__(256) void bucket_k(const int* __restrict__ e_sr,
                                                const int* __restrict__ e_tg,
                                                int* __restrict__ gcur,
                                                int* __restrict__ bkt) {
    __shared__ int bcnt[4][NRANGE];
    __shared__ int bbase[4][NRANGE];
    const int tid = threadIdx.x;
    if (tid < 4 * NRANGE) ((int*)bcnt)[tid] = 0;
    __syncthreads();
    const int g = blockIdx.x * 256 + tid;  // i4 group index over combined edges
    i4 s4, d4;
    if (g < NE4) {
        s4 = *((const i4*)e_sr + g);
        d4 = *((const i4*)e_sr + NE4 + g);
    } else {
        s4 = *((const i4*)e_tg + g - NE4);
        d4 = *((const i4*)e_tg + g);
        s4 += NN;
        d4 += NN;
    }
    const int wv = tid >> 6;
    int rr[4], lr[4];
#pragma unroll
    for (int j = 0; j < 4; ++j) {
        rr[j] = d4[j] / RSZ;
        lr[j] = atomicAdd(&bcnt[wv][rr[j]], 1);
    }
    __syncthreads();
    if (tid < NRANGE) {
        const int t0 = bcnt[0][tid], t1 = bcnt[1][tid];
        const int t2 = bcnt[2][tid], t3 = bcnt[3][tid];
        const int b = atomicAdd(&gcur[tid], t0 + t1 + t2 + t3);
        bbase[0][tid] = b;
        bbase[1][tid] = b + t0;
        bbase[2][tid] = b + t0 + t1;
        bbase[3][tid] = b + t0 + t1 + t2;
    }
    __syncthreads();
#pragma unroll
    for (int j = 0; j < 4; ++j) {
        const int dtl = d4[j] - rr[j] * RSZ;
        bkt[bbase[wv][rr[j]] + lr[j]] = (dtl << 18) | s4[j];
    }
}

// ---------------- hist: per-(range,chunk) LDS histogram -> P[c][node] ----------------
__global__ __launch_bounds__(1024) void hist_k(const int* __restrict__ gcur,
                                               const int* __restrict__ bkt,
                                               int* __restrict__ P) {
    __shared__ int lc[RSZ];  // 50 KB
    const int r = blockIdx.x & (NRANGE - 1);   // low bits -> XCD round-robin
    const int c = blockIdx.x >> 4;
    const int lo = r * RSZ;
    for (int i = threadIdx.x; i < RSZ; i += 1024) lc[i] = 0;
    __syncthreads();
    const int n_r = gcur[r] - r * BCAP;        // exact bucket count
    const int S = (n_r + CH - 1) / CH;
    const int s0 = c * S;
    int s1 = s0 + S; if (s1 > n_r) s1 = n_r;
    for (int v = s0 + threadIdx.x; v < s1; v += 1024) {
        const unsigned int w = (unsigned int)bkt[r * BCAP + v];
        atomicAdd(&lc[w >> 18], 1);
    }
    __syncthreads();
    for (int i = threadIdx.x; i < RSZ; i += 1024) P[c * NT + lo + i] = lc[i];
}

// ---------------- cnt = sum_c P[c][n] ; fused dinv + scanA block sums ----------------
__global__ __launch_bounds__(256) void reduceA_k(const int* __restrict__ P,
                                                 int* __restrict__ cnt,
                                                 float* __restrict__ dinv,
                                                 int* __restrict__ bsum) {
    __shared__ int sh[256];
    const int t = threadIdx.x;
    const int i = blockIdx.x * 256 + t;
    int s = 0;
    if (i < NT) {
#pragma unroll
        for (int c = 0; c < CH; ++c) s += P[c * NT + i];
        cnt[i] = s;
        dinv[i] = rsqrtf((float)(s + 1));  // +1 self-loop
    }
    sh[t] = s;
    __syncthreads();
    for (int off = 128; off > 0; off >>= 1) {
        if (t < off) sh[t] += sh[t + off];
        __syncthreads();
    }
    if (t == 0) bsum[blockIdx.x] = sh[0];
}

__global__ __launch_bounds__(1024) void scanB_k(int* bsum, int* row_ptr) {
    __shared__ int s[1024];
    const int t = threadIdx.x;
    const int v = (t < SB2) ? bsum[t] : 0;
    s[t] = v;
    __syncthreads();
    for (int off = 1; off < 1024; off <<= 1) {
        int add = (t >= off) ? s[t - off] : 0;
        __syncthreads();
        s[t] += add;
        __syncthreads();
    }
    if (t < SB2) bsum[t] = s[t] - v;        // exclusive
    if (t == SB2 - 1) row_ptr[NT] = s[t];   // == ET
}

// ---------------- scanC + base fused: row_ptr + per-(chunk,node) slot bases ----------------
__global__ __launch_bounds__(256) void scanCbase_k(const int* __restrict__ cnt,
                                                   const int* __restrict__ bsum,
                                                   int* __restrict__ row_ptr,
                                                   int* __restrict__ P) {
    __shared__ int s[256];
    const int t = threadIdx.x;
    const int i = blockIdx.x * 256 + t;
    const int v = (i < NT) ? cnt[i] : 0;
    s[t] = v;
    __syncthreads();
    for (int off = 1; off < 256; off <<= 1) {
        int add = (t >= off) ? s[t - off] : 0;
        __syncthreads();
        s[t] += add;
        __syncthreads();
    }
    if (i < NT) {
        const int rp = bsum[blockIdx.x] + s[t] - v;
        row_ptr[i] = rp;
        int run = rp;
#pragma unroll
        for (int c = 0; c < CH; ++c) {
            const int pv = P[c * NT + i];
            P[c * NT + i] = run;
            run += pv;
        }
    }
}

// ---------------- fill: LDS cursors over the dense bucket ----------------
__global__ __launch_bounds__(1024) void fillp_k(const int* __restrict__ gcur,
                                                const int* __restrict__ bkt,
                                                const int* __restrict__ P,  // = base
                                                int* __restrict__ csr_src) {
    __shared__ int cur[RSZ];  // 50 KB
    const int r = blockIdx.x & (NRANGE - 1);
    const int c = blockIdx.x >> 4;
    const int lo = r * RSZ;
    for (int i = threadIdx.x; i < RSZ; i += 1024) cur[i] = P[c * NT + lo + i];
    __syncthreads();
    const int n_r = gcur[r] - r * BCAP;
    const int S = (n_r + CH - 1) / CH;     // identical chunking to hist_k
    const int s0 = c * S;
    int s1 = s0 + S; if (s1 > n_r) s1 = n_r;
    for (int v = s0 + threadIdx.x; v < s1; v += 1024) {
        const unsigned int w = (unsigned int)bkt[r * BCAP + v];
        const int pos = atomicAdd(&cur[w >> 18], 1);
        csr_src[pos] = (int)(w & 0x3FFFFu);  // store: range's csr slice L2-resident
    }
}

// Wt[n][k] = bf16(W[k][n]), both weights in one dispatch; block 0 inits gcur
__global__ __launch_bounds__(256) void convW2_k(const float* __restrict__ W0,
                                                const float* __restrict__ W1,
                                                unsigned short* __restrict__ wt0,
                                                unsigned short* __restrict__ wt1,
                                                int* __restrict__ gcur) {
    int i = blockIdx.x * 256 + threadIdx.x;
    if (blockIdx.x == 0 && threadIdx.x < NRANGE) gcur[threadIdx.x] = threadIdx.x * BCAP;
    if (i >= 2 * DIM * DIM) return;
    const float* W = (i < DIM * DIM) ? W0 : W1;
    unsigned short* wt = (i < DIM * DIM) ? wt0 : wt1;
    const int ii = i & (DIM * DIM - 1);
    const int n = ii & 127, k = ii >> 7;
    wt[n * DIM + k] = f2bf(W[k * DIM + n]);
}

// ---------------- layer-1 GEMM with fused f32->bf16 staging ----------------
__global__ __launch_bounds__(256) void gemmE_k(const float* __restrict__ emb_sr,
                                               const float* __restrict__ emb_tg,
                                               const unsigned short* __restrict__ Wt,
                                               const float* __restrict__ dinv,
                                               unsigned short* __restrict__ Gb) {
    __shared__ unsigned short xs[64 * PAD];   // 17.4 KB
    __shared__ unsigned short ws[128 * PAD];  // 34.8 KB
    const int tid = threadIdx.x;
    const int row0 = blockIdx.x * 64;         // NT % 64 == 0: no clamp needed

    for (int i = tid; i < 128 * 16; i += 256) {
        const int r = i >> 4, o = i & 15;
        *(uint4*)&ws[r * PAD + o * 8] = *(const uint4*)&Wt[r * DIM + o * 8];
    }
    for (int i = tid; i < 64 * 32; i += 256) {  // 64 rows x 32 float4
        const int r = i >> 5, o = i & 31;
        const int gr = row0 + r;
        const float4 v = (gr < NN) ? ((const float4*)emb_sr)[gr * 32 + o]
                                   : ((const float4*)emb_tg)[(gr - NN) * 32 + o];
        ushort4 b;
        b.x = f2bf(v.x); b.y = f2bf(v.y); b.z = f2bf(v.z); b.w = f2bf(v.w);
        *(ushort4*)&xs[r * PAD + o * 4] = b;
    }
    __syncthreads();

    const int wave = tid >> 6;
    const int lane = tid & 63;
    const int m = lane & 15;
    const int quad = lane >> 4;
    const int rbase = wave * 16;

    frag_cd acc[8];
#pragma unroll
    for (int ct = 0; ct < 8; ct++) acc[ct] = (frag_cd){0.f, 0.f, 0.f, 0.f};

#pragma unroll
    for (int ks = 0; ks < 4; ks++) {
        const frag_ab a = *(const frag_ab*)&xs[(rbase + m) * PAD + ks * 32 + quad * 8];
#pragma unroll
        for (int ct = 0; ct < 8; ct++) {
            const frag_ab b = *(const frag_ab*)&ws[(ct * 16 + m) * PAD + ks * 32 + quad * 8];
            acc[ct] = __builtin_amdgcn_mfma_f32_16x16x32_bf16(a, b, acc[ct], 0, 0, 0);
        }
    }

    // C/D layout: col = lane&15, row = quad*4 + reg
#pragma unroll
    for (int r = 0; r < 4; r++) {
        const int grow = row0 + rbase + quad * 4 + r;
        const float dv = dinv[grow];
#pragma unroll
        for (int ct = 0; ct < 8; ct++)
            Gb[grow * DIM + ct * 16 + m] = f2bf(dv * acc[ct][r]);
    }
}

// ---------------- layer-2 GEMM (bf16 input): Gb = dinv ⊙ (Xb @ W) ----------------
__global__ __launch_bounds__(256) void gemm_mfma_k(const unsigned short* __restrict__ Xb,
                                                   const unsigned short* __restrict__ Wt,
                                                   const float* __restrict__ dinv,
                                                   unsigned short* __restrict__ Gb) {
    __shared__ unsigned short xs[64 * PAD];   // 17.4 KB
    __shared__ unsigned short ws[128 * PAD];  // 34.8 KB
    const int tid = threadIdx.x;
    const int row0 = blockIdx.x * 64;

    for (int i = tid; i < 128 * 16; i += 256) {
        const int r = i >> 4, o = i & 15;
        *(uint4*)&ws[r * PAD + o * 8] = *(const uint4*)&Wt[r * DIM + o * 8];
    }
    for (int i = tid; i < 64 * 16; i += 256) {
        const int r = i >> 4, o = i & 15;
        *(uint4*)&xs[r * PAD + o * 8] = *(const uint4*)&Xb[(row0 + r) * DIM + o * 8];
    }
    __syncthreads();

    const int wave = tid >> 6;
    const int lane = tid & 63;
    const int m = lane & 15;
    const int quad = lane >> 4;
    const int rbase = wave * 16;

    frag_cd acc[8];
#pragma unroll
    for (int ct = 0; ct < 8; ct++) acc[ct] = (frag_cd){0.f, 0.f, 0.f, 0.f};

#pragma unroll
    for (int ks = 0; ks < 4; ks++) {
        const frag_ab a = *(const frag_ab*)&xs[(rbase + m) * PAD + ks * 32 + quad * 8];
#pragma unroll
        for (int ct = 0; ct < 8; ct++) {
            const frag_ab b = *(const frag_ab*)&ws[(ct * 16 + m) * PAD + ks * 32 + quad * 8];
            acc[ct] = __builtin_amdgcn_mfma_f32_16x16x32_bf16(a, b, acc[ct], 0, 0, 0);
        }
    }

#pragma unroll
    for (int r = 0; r < 4; r++) {
        const int grow = row0 + rbase + quad * 4 + r;
        const float dv = dinv[grow];
#pragma unroll
        for (int ct = 0; ct < 8; ct++)
            Gb[grow * DIM + ct * 16 + m] = f2bf(dv * acc[ct][r]);
    }
}

// ---------------- fused pull (weightless gather) + residual + ReLU ----------------
// out[t] = relu( dinv[t]*(g[t] + Σ g[src]) + g[t]*sqrt(deg[t]) )
template <bool OUT_BF16>
__global__ __launch_bounds__(256) void pull_k(const int* __restrict__ row_ptr,
                                              const int* __restrict__ csr_src,
                                              const float* __restrict__ dinv,
                                              const unsigned short* __restrict__ Gb,
                                              float* __restrict__ outf,
                                              unsigned short* __restrict__ outb) {
    const int node = (blockIdx.x * 256 + threadIdx.x) >> 6;
    if (node >= NT) return;
    const int lane = threadIdx.x & 63;
    const unsigned int* __restrict__ G2 = (const unsigned int*)Gb;

    const int beg = row_ptr[node];
    const int end = row_ptr[node + 1];
    const float d = dinv[node];
    const float sq = 1.0f / d;  // sqrt(deg)

    const unsigned int gu = G2[node * 64 + lane];
    float sx = bflo(gu);  // self-loop term g[t]
    float sy = bfhi(gu);
    const float hx = sx * sq;  // residual h[t] = g[t]*sqrt(deg)
    const float hy = sy * sq;

    for (int base = beg; base < end; base += 64) {
        int rem = end - base; if (rem > 64) rem = 64;
        const int sl = (lane < rem) ? csr_src[base + lane] : 0;
        int j = 0;
        for (; j + 16 <= rem; j += 16) {  // 16 outstanding gathers
            int ss[16];
            unsigned int mm[16];
#pragma unroll
            for (int q = 0; q < 16; ++q) ss[q] = __shfl(sl, j + q);
#pragma unroll
            for (int q = 0; q < 16; ++q) mm[q] = G2[ss[q] * 64 + lane];
#pragma unroll
            for (int q = 0; q < 16; ++q) { sx += bflo(mm[q]); sy += bfhi(mm[q]); }
        }
        for (; j + 8 <= rem; j += 8) {
            int ss[8];
            unsigned int mm[8];
#pragma unroll
            for (int q = 0; q < 8; ++q) ss[q] = __shfl(sl, j + q);
#pragma unroll
            for (int q = 0; q < 8; ++q) mm[q] = G2[ss[q] * 64 + lane];
#pragma unroll
            for (int q = 0; q < 8; ++q) { sx += bflo(mm[q]); sy += bfhi(mm[q]); }
        }
        for (; j + 4 <= rem; j += 4) {
            int ss[4];
            unsigned int mm[4];
#pragma unroll
            for (int q = 0; q < 4; ++q) ss[q] = __shfl(sl, j + q);
#pragma unroll
            for (int q = 0; q < 4; ++q) mm[q] = G2[ss[q] * 64 + lane];
#pragma unroll
            for (int q = 0; q < 4; ++q) { sx += bflo(mm[q]); sy += bfhi(mm[q]); }
        }
        for (; j < rem; ++j) {
            const int s = __shfl(sl, j);
            const unsigned int mu = G2[s * 64 + lane];
            sx += bflo(mu);
            sy += bfhi(mu);
        }
    }
    const float ax = fmaxf(d * sx + hx, 0.f);
    const float ay = fmaxf(d * sy + hy, 0.f);
    if (OUT_BF16) {
        ((unsigned int*)outb)[node * 64 + lane] =
            (unsigned int)f2bf(ax) | ((unsigned int)f2bf(ay) << 16);
    } else {
        float2 o; o.x = ax; o.y = ay;
        ((float2*)outf)[node * 64 + lane] = o;
    }
}

// ---------------- seed gather (both seed sets in one dispatch) ----------------
__global__ __launch_bounds__(256) void gather2_k(const int* __restrict__ sr_seeds,
                                                 const int* __restrict__ tg_seeds,
                                                 const float* __restrict__ ent,
                                                 float* __restrict__ sr_out,
                                                 float* __restrict__ tg_out) {
    const int gid = blockIdx.x * 256 + threadIdx.x;
    const int s = gid >> 5;
    if (s >= 2 * NS) return;
    const int q = gid & 31;
    const bool tg = s >= NS;
    const int si = tg ? s - NS : s;
    const int node = tg ? tg_seeds[si] + NN : sr_seeds[si];
    float* o = tg ? tg_out : sr_out;
    ((float4*)o)[si * 32 + q] = ((const float4*)ent)[node * 32 + q];
}

extern "C" void kernel_launch(void* const* d_in, const int* in_sizes, int n_in,
                              void* d_out, int out_size, void* d_ws, size_t ws_size,
                              hipStream_t stream) {
    const int* sr_seeds = (const int*)d_in[0];
    const int* tg_seeds = (const int*)d_in[1];
    const int* edges_sr = (const int*)d_in[2];
    const int* edges_tg = (const int*)d_in[3];
    const float* emb_sr = (const float*)d_in[4];
    const float* emb_tg = (const float*)d_in[5];
    const float* W0 = (const float*)d_in[6];
    const float* W1 = (const float*)d_in[7];
    float* out = (float*)d_out;

    // ws layout (4B words): cnt[200704] dinv[200704] row_ptr[200704]
    // bsum[1024] csr_src[ET] wt0+wt1[16384 words] hb[NT*DIM ushort]
    // total = 66.5 MB (R3-proven footprint, unchanged).
    // Inside hb (12.8M words): P[CH*NT]=3.2M then bkt[NRANGE*BCAP]=3.36M
    // words — both dead before gemmE writes hb.  gcur[16] lives in the
    // unused tail of bsum (only [0, SB2) = 782 words are used by scans).
    int* cnt = (int*)d_ws;
    float* dinv = (float*)(cnt + 200704);
    int* row_ptr = (int*)(dinv + 200704);
    int* bsum = row_ptr + 200704;
    int* csr_src = bsum + 1024;
    unsigned short* wt0 = (unsigned short*)(csr_src + ET);
    unsigned short* wt1 = wt0 + DIM * DIM;
    unsigned short* hb = wt1 + DIM * DIM;  // [NT*DIM] bf16 (g buffer)
    int* P = (int*)hb;                     // [CH][NT] ints
    int* bkt = P + CH * NT;                // [NRANGE*BCAP] packed edges
    int* gcur = bsum + 800;                // [16] bucket cursors

    // output layout (floats): sr_seed | tg_seed | ent [NT, DIM]
    // x1 (bf16) borrows the ent region: written by pull<true>, consumed by
    // layer-2 gemm before pull<false> overwrites the region with final f32.
    float* sr_seed_out = out;
    float* tg_seed_out = out + (long long)NS * DIM;
    float* ent = out + (long long)2 * NS * DIM;
    unsigned short* xb = (unsigned short*)ent;

    const int gGemm = (NT + 63) / 64;      // 3125
    const int gPull = NT / 4;              // 50000
    const int gBkt = ET / 1024;            // 3125
    const int gHF = NRANGE * CH;           // 256

    convW2_k<<<(2 * DIM * DIM + 255) / 256, 256, 0, stream>>>(W0, W1, wt0, wt1, gcur);

    bucket_k<<<gBkt, 256, 0, stream>>>(edges_sr, edges_tg, gcur, bkt);
    hist_k<<<gHF, 1024, 0, stream>>>(gcur, bkt, P);
    reduceA_k<<<SB2, 256, 0, stream>>>(P, cnt, dinv, bsum);
    scanB_k<<<1, 1024, 0, stream>>>(bsum, row_ptr);
    scanCbase_k<<<SB2, 256, 0, stream>>>(cnt, bsum, row_ptr, P);
    fillp_k<<<gHF, 1024, 0, stream>>>(gcur, bkt, P, csr_src);

    // layer 1: g1 = dinv ⊙ (bf16(emb)@W0) -> hb (conversion fused into staging)
    gemmE_k<<<gGemm, 256, 0, stream>>>(emb_sr, emb_tg, wt0, dinv, hb);
    pull_k<true><<<gPull, 256, 0, stream>>>(row_ptr, csr_src, dinv, hb, nullptr, xb);
    // layer 2: g2 = dinv ⊙ (x1@W1) -> hb ; ent(f32) overwrites x1's region
    gemm_mfma_k<<<gGemm, 256, 0, stream>>>(xb, wt1, dinv, hb);
    pull_k<false><<<gPull, 256, 0, stream>>>(row_ptr, csr_src, dinv, hb, ent, nullptr);

    const int gSeed = (2 * NS * 32 + 255) / 256;
    gather2_k<<<gSeed, 256, 0, stream>>>(sr_seeds, tg_seeds, ent, sr_seed_out, tg_seed_out);
}